// Round 6
// baseline (701.741 us; speedup 1.0000x reference)
//
#include <hip/hip_runtime.h>
#include <hip/hip_bf16.h>
#include <stdint.h>

// Problem constants (match reference)
#define B_SZ   16384
#define IN_DIM 1024
#define H1     2048
#define H2     2048
#define HID    1024
#define SPEC_H 2048
#define NE     8
#define MAX_TILES 136   // 8 XCDs x 17 tiles exactly

typedef __bf16 bf16x8 __attribute__((ext_vector_type(8)));
typedef float  f32x4  __attribute__((ext_vector_type(4)));

__device__ __forceinline__ ushort f2bf(float f) {
  uint32_t u = __float_as_uint(f);
  u += 0x7FFF + ((u >> 16) & 1);
  return (ushort)(u >> 16);
}

__device__ __forceinline__ void gl_lds16(const void* g, void* l) {
  __builtin_amdgcn_global_load_lds(
      (const __attribute__((address_space(1))) void*)g,
      (__attribute__((address_space(3))) void*)l, 16, 0, 0);
}

// ---------------- batched transpose-cast (all 4 weights, one launch) --------

struct TransDesc { const float* src; ushort* dst; int K, N, nx, base; };
struct TransArgs { TransDesc d[4]; };

__global__ void transpose_all(TransArgs ta) {
  __shared__ float tile[64][65];  // tile[n][k]
  int g = blockIdx.x;
  int wsel = 0;
#pragma unroll
  for (int i = 1; i < 4; ++i)
    if (g >= ta.d[i].base) wsel = i;
  TransDesc dd = ta.d[wsel];
  int local = g - dd.base;
  int per = dd.nx * (dd.K >> 6);       // tiles per batch slab
  int z = local / per;
  int r = local - z * per;
  int bx = r % dd.nx, by = r / dd.nx;
  int n0 = bx * 64, k0 = by * 64;
  const float* src = dd.src + (size_t)z * dd.K * dd.N;
  ushort* dst = dd.dst + (size_t)z * dd.K * dd.N;
  int t = threadIdx.x;
  int lk = t >> 4;
  int ln4 = (t & 15) * 4;
#pragma unroll
  for (int j = 0; j < 4; ++j) {
    int k = lk + j * 16;
    float4 v = *(const float4*)(src + (size_t)(k0 + k) * dd.N + n0 + ln4);
    tile[ln4 + 0][k] = v.x;
    tile[ln4 + 1][k] = v.y;
    tile[ln4 + 2][k] = v.z;
    tile[ln4 + 3][k] = v.w;
  }
  __syncthreads();
  int kc = (t & 15) * 4;
  int nb = t >> 4;
#pragma unroll
  for (int j = 0; j < 4; ++j) {
    int nn = nb + j * 16;
    ushort4 o;
    o.x = f2bf(tile[nn][kc + 0]);
    o.y = f2bf(tile[nn][kc + 1]);
    o.z = f2bf(tile[nn][kc + 2]);
    o.w = f2bf(tile[nn][kc + 3]);
    *(ushort4*)(dst + (size_t)(n0 + nn) * dd.K + k0 + kc) = o;
  }
}

// ---------------- routing ----------------

__global__ void count_init_k(const int* __restrict__ d, int* __restrict__ counts,
                             const float* __restrict__ b2, float* __restrict__ out) {
  int i = blockIdx.x * 256 + threadIdx.x;
  if (i < B_SZ) {
    int e = d[i];
    atomicAdd(&counts[e], 1);
    out[i] = b2[e];  // spec_b2[e][0]
  }
}

__global__ void build_k(const int* __restrict__ counts, int* __restrict__ catalog,
                        int* __restrict__ poff, int* __restrict__ cursors) {
  if (threadIdx.x == 0) {
    int off = 0;
    for (int e = 0; e < NE; ++e) {
      poff[e] = off * 128;
      int nt = (counts[e] + 127) >> 7;
      for (int i = 0; i < nt; ++i) catalog[off + i] = e;
      off += nt;
      cursors[e] = 0;
    }
    for (int i = off; i < MAX_TILES; ++i) catalog[i] = -1;
  }
}

__global__ void scatter_k(const int* __restrict__ d, const int* __restrict__ poff,
                          int* __restrict__ cursors, int* __restrict__ perm) {
  int i = blockIdx.x * 256 + threadIdx.x;
  if (i < B_SZ) {
    int e = d[i];
    int p = atomicAdd(&cursors[e], 1);
    perm[poff[e] + p] = i;
  }
}

// ---------------- G1: fused-cast GEMM  z1 = relu(x_f32 @ W0t^T + b0) ---------
// A staged into LDS as raw fp32 (32 KB), converted to bf16 at fragment read.
// 128x128 tile, BK=64. XCD swizzle as gemm_bias.

__global__ __launch_bounds__(256, 2) void gemm_cast(
    const float* __restrict__ A, const ushort* __restrict__ Bt,
    const float* __restrict__ bias, ushort* __restrict__ C,
    int M, int N, int K, int lognx) {
  __shared__ __align__(16) float  lA4[128 * 64];   // 32 KB fp32
  __shared__ __align__(16) ushort lB[128 * 64];    // 16 KB bf16
  const int t = threadIdx.x;
  const int h = blockIdx.x;
  const int g = h >> 3;
  const int nx = 1 << lognx;
  const int by = (h & 7) + ((g >> lognx) << 3);
  const int bx = g & (nx - 1);
  const int m0 = by * 128, n0 = bx * 128;
  const int w = t >> 6, lane = t & 63;
  const int wm = (w >> 1) * 64, wn = (w & 1) * 64;
  const int q = lane >> 4, rl = lane & 15;

  f32x4 acc[4][4];
#pragma unroll
  for (int mi = 0; mi < 4; ++mi)
#pragma unroll
    for (int ni = 0; ni < 4; ++ni) acc[mi][ni] = 0.0f;

  const int rowA_s = t >> 4;          // 0..15 within 16-row round
  const int chA_s  = (t & 15) ^ (t >> 4);  // physical 16B chunk (swizzled)
  const int rowB_s = t >> 3;
  const int chB_s  = t & 7;

  for (int k0 = 0; k0 < K; k0 += 64) {
    __syncthreads();
#pragma unroll
    for (int j = 0; j < 8; ++j) {       // A fp32: 8 rounds x 16 rows
      int row = j * 16 + rowA_s;
      gl_lds16(A + (size_t)(m0 + row) * K + k0 + chA_s * 4, lA4 + j * 1024 + w * 256);
    }
#pragma unroll
    for (int j = 0; j < 4; ++j) {       // B bf16: 4 rounds x 32 rows
      int row = j * 32 + rowB_s;
      int gch = chB_s ^ (row & 7);
      gl_lds16(Bt + (size_t)(n0 + row) * K + k0 + gch * 8, lB + j * 2048 + w * 512);
    }
    __syncthreads();
#pragma unroll
    for (int kk = 0; kk < 2; ++kk) {
      bf16x8 af[4], bfr[4];
      int c0 = kk * 8 + q * 2;
#pragma unroll
      for (int i = 0; i < 4; ++i) {
        const float* rowp = lA4 + (wm + i * 16 + rl) * 64;
        float4 u0 = *(const float4*)(rowp + ((c0 ^ rl) * 4));
        float4 u1 = *(const float4*)(rowp + (((c0 + 1) ^ rl) * 4));
        uint32_t p0 = f2bf(u0.x) | ((uint32_t)f2bf(u0.y) << 16);
        uint32_t p1 = f2bf(u0.z) | ((uint32_t)f2bf(u0.w) << 16);
        uint32_t p2 = f2bf(u1.x) | ((uint32_t)f2bf(u1.y) << 16);
        uint32_t p3 = f2bf(u1.z) | ((uint32_t)f2bf(u1.w) << 16);
        int4 pk = {(int)p0, (int)p1, (int)p2, (int)p3};
        af[i] = __builtin_bit_cast(bf16x8, pk);
        int pc = (kk * 4 + q) ^ (rl & 7);
        bfr[i] = __builtin_bit_cast(bf16x8, *(const int4*)(lB + (wn + i * 16 + rl) * 64 + pc * 8));
      }
#pragma unroll
      for (int mi = 0; mi < 4; ++mi)
#pragma unroll
        for (int ni = 0; ni < 4; ++ni)
          acc[mi][ni] = __builtin_amdgcn_mfma_f32_16x16x32_bf16(af[mi], bfr[ni], acc[mi][ni], 0, 0, 0);
    }
  }

  float bv[4];
#pragma unroll
  for (int ni = 0; ni < 4; ++ni) bv[ni] = bias[n0 + wn + ni * 16 + rl];
#pragma unroll
  for (int mi = 0; mi < 4; ++mi) {
    int rg = m0 + wm + mi * 16 + q * 4;
#pragma unroll
    for (int r = 0; r < 4; ++r) {
#pragma unroll
      for (int ni = 0; ni < 4; ++ni) {
        float v = fmaxf(acc[mi][ni][r] + bv[ni], 0.0f);
        C[(size_t)(rg + r) * N + n0 + wn + ni * 16 + rl] = f2bf(v);
      }
    }
  }
}

// ---------------- 128x128 bf16 GEMM (G3) ----------------

template <int RELU>
__global__ __launch_bounds__(256, 2) void gemm_bias(
    const ushort* __restrict__ A, const ushort* __restrict__ Bt,
    const float* __restrict__ bias, ushort* __restrict__ C,
    int M, int N, int K, int lognx) {
  __shared__ __align__(16) ushort lA[128 * 64];
  __shared__ __align__(16) ushort lB[128 * 64];
  const int t = threadIdx.x;
  const int h = blockIdx.x;
  const int g = h >> 3;
  const int nx = 1 << lognx;
  const int by = (h & 7) + ((g >> lognx) << 3);
  const int bx = g & (nx - 1);
  const int m0 = by * 128, n0 = bx * 128;
  const int w = t >> 6, lane = t & 63;
  const int wm = (w >> 1) * 64, wn = (w & 1) * 64;
  const int q = lane >> 4, rl = lane & 15;

  f32x4 acc[4][4];
#pragma unroll
  for (int mi = 0; mi < 4; ++mi)
#pragma unroll
    for (int ni = 0; ni < 4; ++ni) acc[mi][ni] = 0.0f;

  const int row_s = t >> 3;
  const int pch_s = t & 7;

  for (int k0 = 0; k0 < K; k0 += 64) {
    __syncthreads();
#pragma unroll
    for (int j = 0; j < 4; ++j) {
      int row = j * 32 + row_s;
      int gch = pch_s ^ (row & 7);
      gl_lds16(A + (size_t)(m0 + row) * K + k0 + gch * 8, lA + j * 2048 + w * 512);
      gl_lds16(Bt + (size_t)(n0 + row) * K + k0 + gch * 8, lB + j * 2048 + w * 512);
    }
    __syncthreads();
#pragma unroll
    for (int kk = 0; kk < 2; ++kk) {
      bf16x8 af[4], bfr[4];
#pragma unroll
      for (int i = 0; i < 4; ++i) {
        int pc = (kk * 4 + q) ^ (rl & 7);
        af[i]  = __builtin_bit_cast(bf16x8, *(const int4*)(lA + (wm + i * 16 + rl) * 64 + pc * 8));
        bfr[i] = __builtin_bit_cast(bf16x8, *(const int4*)(lB + (wn + i * 16 + rl) * 64 + pc * 8));
      }
#pragma unroll
      for (int mi = 0; mi < 4; ++mi)
#pragma unroll
        for (int ni = 0; ni < 4; ++ni)
          acc[mi][ni] = __builtin_amdgcn_mfma_f32_16x16x32_bf16(af[mi], bfr[ni], acc[mi][ni], 0, 0, 0);
    }
  }

  float bv[4];
#pragma unroll
  for (int ni = 0; ni < 4; ++ni) bv[ni] = bias[n0 + wn + ni * 16 + rl];
#pragma unroll
  for (int mi = 0; mi < 4; ++mi) {
    int rg = m0 + wm + mi * 16 + q * 4;
#pragma unroll
    for (int r = 0; r < 4; ++r) {
#pragma unroll
      for (int ni = 0; ni < 4; ++ni) {
        float v = acc[mi][ni][r] + bv[ni];
        if (RELU) v = fmaxf(v, 0.0f);
        C[(size_t)(rg + r) * N + n0 + wn + ni * 16 + rl] = f2bf(v);
      }
    }
  }
}

// ---------------- 256x128 bf16 GEMM (G2) ----------------

template <int RELU>
__global__ __launch_bounds__(256, 2) void gemm_bias_256(
    const ushort* __restrict__ A, const ushort* __restrict__ Bt,
    const float* __restrict__ bias, ushort* __restrict__ C,
    int M, int N, int K, int lognx) {
  __shared__ __align__(16) ushort lA[256 * 64];
  __shared__ __align__(16) ushort lB[128 * 64];
  const int t = threadIdx.x;
  const int h = blockIdx.x;
  const int g = h >> 3;
  const int nx = 1 << lognx;
  const int by = (h & 7) + ((g >> lognx) << 3);
  const int bx = g & (nx - 1);
  const int m0 = by * 256, n0 = bx * 128;
  const int w = t >> 6, lane = t & 63;
  const int wm = (w >> 1) * 128, wn = (w & 1) * 64;
  const int q = lane >> 4, rl = lane & 15;

  f32x4 acc[8][4];
#pragma unroll
  for (int mi = 0; mi < 8; ++mi)
#pragma unroll
    for (int ni = 0; ni < 4; ++ni) acc[mi][ni] = 0.0f;

  const int row_s = t >> 3;
  const int pch_s = t & 7;

  for (int k0 = 0; k0 < K; k0 += 64) {
    __syncthreads();
#pragma unroll
    for (int j = 0; j < 8; ++j) {
      int row = j * 32 + row_s;
      int gch = pch_s ^ (row & 7);
      gl_lds16(A + (size_t)(m0 + row) * K + k0 + gch * 8, lA + j * 2048 + w * 512);
    }
#pragma unroll
    for (int j = 0; j < 4; ++j) {
      int row = j * 32 + row_s;
      int gch = pch_s ^ (row & 7);
      gl_lds16(Bt + (size_t)(n0 + row) * K + k0 + gch * 8, lB + j * 2048 + w * 512);
    }
    __syncthreads();
#pragma unroll
    for (int kk = 0; kk < 2; ++kk) {
      bf16x8 bfr[4];
#pragma unroll
      for (int i = 0; i < 4; ++i) {
        int pc = (kk * 4 + q) ^ (rl & 7);
        bfr[i] = __builtin_bit_cast(bf16x8, *(const int4*)(lB + (wn + i * 16 + rl) * 64 + pc * 8));
      }
#pragma unroll
      for (int mi = 0; mi < 8; ++mi) {
        int pc = (kk * 4 + q) ^ (rl & 7);
        bf16x8 af = __builtin_bit_cast(bf16x8, *(const int4*)(lA + (wm + mi * 16 + rl) * 64 + pc * 8));
#pragma unroll
        for (int ni = 0; ni < 4; ++ni)
          acc[mi][ni] = __builtin_amdgcn_mfma_f32_16x16x32_bf16(af, bfr[ni], acc[mi][ni], 0, 0, 0);
      }
    }
  }

  float bv[4];
#pragma unroll
  for (int ni = 0; ni < 4; ++ni) bv[ni] = bias[n0 + wn + ni * 16 + rl];
#pragma unroll
  for (int mi = 0; mi < 8; ++mi) {
    int rg = m0 + wm + mi * 16 + q * 4;
#pragma unroll
    for (int r = 0; r < 4; ++r) {
#pragma unroll
      for (int ni = 0; ni < 4; ++ni) {
        float v = acc[mi][ni][r] + bv[ni];
        if (RELU) v = fmaxf(v, 0.0f);
        C[(size_t)(rg + r) * N + n0 + wn + ni * 16 + rl] = f2bf(v);
      }
    }
  }
}

// ---------------- fused expert stage (bounds-aware, XCD-partitioned) --------

__global__ __launch_bounds__(256, 2) void expert_fused(
    const ushort* __restrict__ Z, const ushort* __restrict__ W1t,
    const float* __restrict__ b1, const float* __restrict__ w2,
    const int* __restrict__ perm, const int* __restrict__ catalog,
    const int* __restrict__ poff, const int* __restrict__ counts,
    float* __restrict__ out) {
  const int id = blockIdx.x;
  const int tile = (id & 7) * 17 + ((id >> 3) >> 4);
  const int ycol = (id >> 3) & 15;
  int e = catalog[tile];
  if (e < 0) return;
  __shared__ __align__(16) ushort lA[128 * 64];
  __shared__ __align__(16) ushort lB[128 * 64];
  __shared__ int perml[128];
  __shared__ float ysum[128];
  const int t = threadIdx.x;
  if (t < 128) {
    int slot = tile * 128 + t;
    int rel = slot - poff[e];
    perml[t] = (rel < counts[e]) ? perm[slot] : -1;
    ysum[t] = 0.0f;
  }
  __syncthreads();

  const int n0 = ycol * 128;
  const ushort* Bt = W1t + (size_t)e * SPEC_H * HID;
  const float* b1e = b1 + (size_t)e * SPEC_H;
  const float* w2e = w2 + (size_t)e * SPEC_H;
  const int w = t >> 6, lane = t & 63;
  const int wm = (w >> 1) * 64, wn = (w & 1) * 64;
  const int q = lane >> 4, rl = lane & 15;

  f32x4 acc[4][4];
#pragma unroll
  for (int mi = 0; mi < 4; ++mi)
#pragma unroll
    for (int ni = 0; ni < 4; ++ni) acc[mi][ni] = 0.0f;

  const int row_s = t >> 3;
  const int pch_s = t & 7;

  for (int k0 = 0; k0 < HID; k0 += 64) {
    __syncthreads();
#pragma unroll
    for (int j = 0; j < 4; ++j) {
      int row = j * 32 + row_s;
      int gch = pch_s ^ (row & 7);
      int zr = perml[row];
      zr = zr < 0 ? 0 : zr;
      gl_lds16(Z + (size_t)zr * HID + k0 + gch * 8, lA + j * 2048 + w * 512);
      gl_lds16(Bt + (size_t)(n0 + row) * HID + k0 + gch * 8, lB + j * 2048 + w * 512);
    }
    __syncthreads();
#pragma unroll
    for (int kk = 0; kk < 2; ++kk) {
      bf16x8 af[4], bfr[4];
#pragma unroll
      for (int i = 0; i < 4; ++i) {
        int pc = (kk * 4 + q) ^ (rl & 7);
        af[i]  = __builtin_bit_cast(bf16x8, *(const int4*)(lA + (wm + i * 16 + rl) * 64 + pc * 8));
        bfr[i] = __builtin_bit_cast(bf16x8, *(const int4*)(lB + (wn + i * 16 + rl) * 64 + pc * 8));
      }
#pragma unroll
      for (int mi = 0; mi < 4; ++mi)
#pragma unroll
        for (int ni = 0; ni < 4; ++ni)
          acc[mi][ni] = __builtin_amdgcn_mfma_f32_16x16x32_bf16(af[mi], bfr[ni], acc[mi][ni], 0, 0, 0);
    }
  }

  float w2v[4], b1v[4];
#pragma unroll
  for (int ni = 0; ni < 4; ++ni) {
    int n = n0 + wn + ni * 16 + rl;
    w2v[ni] = w2e[n];
    b1v[ni] = b1e[n];
  }
#pragma unroll
  for (int mi = 0; mi < 4; ++mi) {
#pragma unroll
    for (int r = 0; r < 4; ++r) {
      float p = 0.0f;
#pragma unroll
      for (int ni = 0; ni < 4; ++ni) {
        float h = acc[mi][ni][r] + b1v[ni];
        h = fmaxf(h, 0.0f);
        p += h * w2v[ni];
      }
      p += __shfl_xor(p, 1);
      p += __shfl_xor(p, 2);
      p += __shfl_xor(p, 4);
      p += __shfl_xor(p, 8);
      if (rl == 0) atomicAdd(&ysum[wm + mi * 16 + q * 4 + r], p);
    }
  }
  __syncthreads();
  if (t < 128) {
    int orow = perml[t];
    if (orow >= 0) atomicAdd(&out[orow], ysum[t]);
  }
}

// ---------------- host ----------------

extern "C" void kernel_launch(void* const* d_in, const int* in_sizes, int n_in,
                              void* d_out, int out_size, void* d_ws, size_t ws_size,
                              hipStream_t stream) {
  const float* x   = (const float*)d_in[0];
  const int*   d   = (const int*)d_in[1];
  const float* eW0 = (const float*)d_in[2];
  const float* eb0 = (const float*)d_in[3];
  const float* eW1 = (const float*)d_in[4];
  const float* eb1 = (const float*)d_in[5];
  const float* eW2 = (const float*)d_in[6];
  const float* eb2 = (const float*)d_in[7];
  const float* sW1 = (const float*)d_in[8];
  const float* sb1 = (const float*)d_in[9];
  const float* sW2 = (const float*)d_in[10];
  const float* sb2 = (const float*)d_in[11];
  float* out = (float*)d_out;

  // fixed: weights bf16 (48 MiB) + Zb (32 MiB) + routing (~0.1) = ~81 MiB
  // per-chunk: z1_c + z2_c = CH * (2048+2048) * 2 = CH*8192 bytes (no xb now)
  const size_t fixed = ((size_t)(4 + 8 + 4 + 32 + 32) << 20) + (1 << 20);
  int CH = 4096;
  if (ws_size >= fixed + (size_t)16384 * 8192) CH = 16384;      // ~209 MiB
  else if (ws_size >= fixed + (size_t)8192 * 8192) CH = 8192;   // ~145 MiB

  char* p = (char*)d_ws;
  ushort* W0t  = (ushort*)p; p += (size_t)IN_DIM * H1 * 2;
  ushort* W1t  = (ushort*)p; p += (size_t)H1 * H2 * 2;
  ushort* W2t  = (ushort*)p; p += (size_t)H2 * HID * 2;
  ushort* sW1t = (ushort*)p; p += (size_t)NE * HID * SPEC_H * 2;
  ushort* Zb   = (ushort*)p; p += (size_t)B_SZ * HID * 2;
  int* counts  = (int*)p; p += 64;
  int* cursors = (int*)p; p += 64;
  int* poff    = (int*)p; p += 64;
  int* catalog = (int*)p; p += 1024;
  int* perm    = (int*)p; p += (size_t)MAX_TILES * 128 * 4;
  p = (char*)(((uintptr_t)p + 255) & ~(uintptr_t)255);
  ushort* z1_c = (ushort*)p; p += (size_t)CH * H1 * 2;
  ushort* z2_c = (ushort*)p; p += (size_t)CH * H2 * 2;

  hipMemsetAsync(counts, 0, 64, stream);

  // routing
  count_init_k<<<B_SZ / 256, 256, 0, stream>>>(d, counts, sb2, out);
  build_k<<<1, 64, 0, stream>>>(counts, catalog, poff, cursors);
  scatter_k<<<B_SZ / 256, 256, 0, stream>>>(d, poff, cursors, perm);

  // all weight transposes in one launch (6144 tile-blocks)
  TransArgs ta;
  ta.d[0] = {eW0, W0t, IN_DIM, H1, H1 / 64, 0};                  // 512 tiles
  ta.d[1] = {eW1, W1t, H1, H2, H2 / 64, 512};                    // 1024
  ta.d[2] = {eW2, W2t, H2, HID, HID / 64, 1536};                 // 512
  ta.d[3] = {sW1, sW1t, HID, SPEC_H, SPEC_H / 64, 2048};         // 8*512=4096
  transpose_all<<<6144, 256, 0, stream>>>(ta);

  // encoder: x -(fused cast GEMM)-> z1 -> z2 -> Zb
  for (int c = 0; c < B_SZ; c += CH) {
    gemm_cast<<<(CH / 128) * (H1 / 128), 256, 0, stream>>>(
        x + (size_t)c * IN_DIM, W0t, eb0, z1_c, CH, H1, IN_DIM, 4);
    gemm_bias_256<1><<<(CH / 256) * (H2 / 128), 256, 0, stream>>>(
        z1_c, W1t, eb1, z2_c, CH, H2, H1, 4);
    gemm_bias<0><<<(CH / 128) * (HID / 128), 256, 0, stream>>>(
        z2_c, W2t, eb2, Zb + (size_t)c * HID, CH, HID, H2, 3);
  }

  // fused expert stage on full routed batch
  expert_fused<<<MAX_TILES * 16, 256, 0, stream>>>(
      Zb, sW1t, sb1, sW2, perm, catalog, poff, counts, out);
}

// Round 7
// 662.976 us; speedup vs baseline: 1.0585x; 1.0585x over previous
//
#include <hip/hip_runtime.h>
#include <hip/hip_bf16.h>
#include <stdint.h>

// Problem constants (match reference)
#define B_SZ   16384
#define IN_DIM 1024
#define H1     2048
#define H2     2048
#define HID    1024
#define SPEC_H 2048
#define NE     8
#define MAX_TILES 136   // 8 XCDs x 17 tiles exactly

typedef __bf16 bf16x8 __attribute__((ext_vector_type(8)));
typedef float  f32x4  __attribute__((ext_vector_type(4)));

__device__ __forceinline__ ushort f2bf(float f) {
  uint32_t u = __float_as_uint(f);
  u += 0x7FFF + ((u >> 16) & 1);
  return (ushort)(u >> 16);
}

__device__ __forceinline__ void gl_lds16(const void* g, void* l) {
  __builtin_amdgcn_global_load_lds(
      (const __attribute__((address_space(1))) void*)g,
      (__attribute__((address_space(3))) void*)l, 16, 0, 0);
}

// ---------------- fused prep: 4 transposes + x-cast + count/out-init --------

struct TransDesc { const float* src; ushort* dst; int K, N, nx, base; };

struct PrepArgs {
  TransDesc td[4];
  const float* x; ushort* xb;
  const int* d; int* counts; const float* sb2; float* out;
  int castBase;   // first cast block
  int cntBase;    // first count block
};

__global__ void prep_all(PrepArgs pa) {
  int g = blockIdx.x;
  int t = threadIdx.x;
  if (g >= pa.cntBase) {
    // count + out-init: 64 blocks x 256
    int i = (g - pa.cntBase) * 256 + t;
    int e = pa.d[i];
    atomicAdd(&pa.counts[e], 1);
    pa.out[i] = pa.sb2[e];     // spec_b2[e][0]
    return;
  }
  if (g >= pa.castBase) {
    // x fp32 -> bf16, 8 elems/thread
    size_t i = (size_t)(g - pa.castBase) * 2048 + (size_t)t * 8;
    float4 v0 = *(const float4*)(pa.x + i);
    float4 v1 = *(const float4*)(pa.x + i + 4);
    uint32_t p0 = f2bf(v0.x) | ((uint32_t)f2bf(v0.y) << 16);
    uint32_t p1 = f2bf(v0.z) | ((uint32_t)f2bf(v0.w) << 16);
    uint32_t p2 = f2bf(v1.x) | ((uint32_t)f2bf(v1.y) << 16);
    uint32_t p3 = f2bf(v1.z) | ((uint32_t)f2bf(v1.w) << 16);
    int4 pk = {(int)p0, (int)p1, (int)p2, (int)p3};
    *(int4*)(pa.xb + i) = pk;
    return;
  }
  // weight transpose-cast
  __shared__ float tile[64][65];  // tile[n][k]
  int wsel = 0;
#pragma unroll
  for (int i = 1; i < 4; ++i)
    if (g >= pa.td[i].base) wsel = i;
  TransDesc dd = pa.td[wsel];
  int local = g - dd.base;
  int per = dd.nx * (dd.K >> 6);
  int z = local / per;
  int r = local - z * per;
  int bx = r % dd.nx, by = r / dd.nx;
  int n0 = bx * 64, k0 = by * 64;
  const float* src = dd.src + (size_t)z * dd.K * dd.N;
  ushort* dst = dd.dst + (size_t)z * dd.K * dd.N;
  int lk = t >> 4;
  int ln4 = (t & 15) * 4;
#pragma unroll
  for (int j = 0; j < 4; ++j) {
    int k = lk + j * 16;
    float4 v = *(const float4*)(src + (size_t)(k0 + k) * dd.N + n0 + ln4);
    tile[ln4 + 0][k] = v.x;
    tile[ln4 + 1][k] = v.y;
    tile[ln4 + 2][k] = v.z;
    tile[ln4 + 3][k] = v.w;
  }
  __syncthreads();
  int kc = (t & 15) * 4;
  int nb = t >> 4;
#pragma unroll
  for (int j = 0; j < 4; ++j) {
    int nn = nb + j * 16;
    ushort4 o;
    o.x = f2bf(tile[nn][kc + 0]);
    o.y = f2bf(tile[nn][kc + 1]);
    o.z = f2bf(tile[nn][kc + 2]);
    o.w = f2bf(tile[nn][kc + 3]);
    *(ushort4*)(dst + (size_t)(n0 + nn) * dd.K + k0 + kc) = o;
  }
}

// ---------------- routing ----------------

__global__ void build_k(const int* __restrict__ counts, int* __restrict__ catalog,
                        int* __restrict__ poff, int* __restrict__ cursors) {
  if (threadIdx.x == 0) {
    int off = 0;
    for (int e = 0; e < NE; ++e) {
      poff[e] = off * 128;
      int nt = (counts[e] + 127) >> 7;
      for (int i = 0; i < nt; ++i) catalog[off + i] = e;
      off += nt;
      cursors[e] = 0;
    }
    for (int i = off; i < MAX_TILES; ++i) catalog[i] = -1;
  }
}

__global__ void scatter_k(const int* __restrict__ d, const int* __restrict__ poff,
                          int* __restrict__ cursors, int* __restrict__ perm) {
  int i = blockIdx.x * 256 + threadIdx.x;
  if (i < B_SZ) {
    int e = d[i];
    int p = atomicAdd(&cursors[e], 1);
    perm[poff[e] + p] = i;
  }
}

// ---------------- 128x128 bf16 GEMM (G1/G3) ----------------

template <int RELU>
__global__ __launch_bounds__(256, 2) void gemm_bias(
    const ushort* __restrict__ A, const ushort* __restrict__ Bt,
    const float* __restrict__ bias, ushort* __restrict__ C,
    int M, int N, int K, int lognx) {
  __shared__ __align__(16) ushort lA[128 * 64];
  __shared__ __align__(16) ushort lB[128 * 64];
  const int t = threadIdx.x;
  const int h = blockIdx.x;
  const int g = h >> 3;
  const int nx = 1 << lognx;
  const int by = (h & 7) + ((g >> lognx) << 3);
  const int bx = g & (nx - 1);
  const int m0 = by * 128, n0 = bx * 128;
  const int w = t >> 6, lane = t & 63;
  const int wm = (w >> 1) * 64, wn = (w & 1) * 64;
  const int q = lane >> 4, rl = lane & 15;

  f32x4 acc[4][4];
#pragma unroll
  for (int mi = 0; mi < 4; ++mi)
#pragma unroll
    for (int ni = 0; ni < 4; ++ni) acc[mi][ni] = 0.0f;

  const int row_s = t >> 3;
  const int pch_s = t & 7;

  for (int k0 = 0; k0 < K; k0 += 64) {
    __syncthreads();
#pragma unroll
    for (int j = 0; j < 4; ++j) {
      int row = j * 32 + row_s;
      int gch = pch_s ^ (row & 7);
      gl_lds16(A + (size_t)(m0 + row) * K + k0 + gch * 8, lA + j * 2048 + w * 512);
      gl_lds16(Bt + (size_t)(n0 + row) * K + k0 + gch * 8, lB + j * 2048 + w * 512);
    }
    __syncthreads();
#pragma unroll
    for (int kk = 0; kk < 2; ++kk) {
      bf16x8 af[4], bfr[4];
#pragma unroll
      for (int i = 0; i < 4; ++i) {
        int pc = (kk * 4 + q) ^ (rl & 7);
        af[i]  = __builtin_bit_cast(bf16x8, *(const int4*)(lA + (wm + i * 16 + rl) * 64 + pc * 8));
        bfr[i] = __builtin_bit_cast(bf16x8, *(const int4*)(lB + (wn + i * 16 + rl) * 64 + pc * 8));
      }
#pragma unroll
      for (int mi = 0; mi < 4; ++mi)
#pragma unroll
        for (int ni = 0; ni < 4; ++ni)
          acc[mi][ni] = __builtin_amdgcn_mfma_f32_16x16x32_bf16(af[mi], bfr[ni], acc[mi][ni], 0, 0, 0);
    }
  }

  float bv[4];
#pragma unroll
  for (int ni = 0; ni < 4; ++ni) bv[ni] = bias[n0 + wn + ni * 16 + rl];
#pragma unroll
  for (int mi = 0; mi < 4; ++mi) {
    int rg = m0 + wm + mi * 16 + q * 4;
#pragma unroll
    for (int r = 0; r < 4; ++r) {
#pragma unroll
      for (int ni = 0; ni < 4; ++ni) {
        float v = acc[mi][ni][r] + bv[ni];
        if (RELU) v = fmaxf(v, 0.0f);
        C[(size_t)(rg + r) * N + n0 + wn + ni * 16 + rl] = f2bf(v);
      }
    }
  }
}

// ---------------- 256x128 bf16 GEMM (G2) ----------------

template <int RELU>
__global__ __launch_bounds__(256, 2) void gemm_bias_256(
    const ushort* __restrict__ A, const ushort* __restrict__ Bt,
    const float* __restrict__ bias, ushort* __restrict__ C,
    int M, int N, int K, int lognx) {
  __shared__ __align__(16) ushort lA[256 * 64];
  __shared__ __align__(16) ushort lB[128 * 64];
  const int t = threadIdx.x;
  const int h = blockIdx.x;
  const int g = h >> 3;
  const int nx = 1 << lognx;
  const int by = (h & 7) + ((g >> lognx) << 3);
  const int bx = g & (nx - 1);
  const int m0 = by * 256, n0 = bx * 128;
  const int w = t >> 6, lane = t & 63;
  const int wm = (w >> 1) * 128, wn = (w & 1) * 64;
  const int q = lane >> 4, rl = lane & 15;

  f32x4 acc[8][4];
#pragma unroll
  for (int mi = 0; mi < 8; ++mi)
#pragma unroll
    for (int ni = 0; ni < 4; ++ni) acc[mi][ni] = 0.0f;

  const int row_s = t >> 3;
  const int pch_s = t & 7;

  for (int k0 = 0; k0 < K; k0 += 64) {
    __syncthreads();
#pragma unroll
    for (int j = 0; j < 8; ++j) {
      int row = j * 32 + row_s;
      int gch = pch_s ^ (row & 7);
      gl_lds16(A + (size_t)(m0 + row) * K + k0 + gch * 8, lA + j * 2048 + w * 512);
    }
#pragma unroll
    for (int j = 0; j < 4; ++j) {
      int row = j * 32 + row_s;
      int gch = pch_s ^ (row & 7);
      gl_lds16(Bt + (size_t)(n0 + row) * K + k0 + gch * 8, lB + j * 2048 + w * 512);
    }
    __syncthreads();
#pragma unroll
    for (int kk = 0; kk < 2; ++kk) {
      bf16x8 bfr[4];
#pragma unroll
      for (int i = 0; i < 4; ++i) {
        int pc = (kk * 4 + q) ^ (rl & 7);
        bfr[i] = __builtin_bit_cast(bf16x8, *(const int4*)(lB + (wn + i * 16 + rl) * 64 + pc * 8));
      }
#pragma unroll
      for (int mi = 0; mi < 8; ++mi) {
        int pc = (kk * 4 + q) ^ (rl & 7);
        bf16x8 af = __builtin_bit_cast(bf16x8, *(const int4*)(lA + (wm + mi * 16 + rl) * 64 + pc * 8));
#pragma unroll
        for (int ni = 0; ni < 4; ++ni)
          acc[mi][ni] = __builtin_amdgcn_mfma_f32_16x16x32_bf16(af, bfr[ni], acc[mi][ni], 0, 0, 0);
      }
    }
  }

  float bv[4];
#pragma unroll
  for (int ni = 0; ni < 4; ++ni) bv[ni] = bias[n0 + wn + ni * 16 + rl];
#pragma unroll
  for (int mi = 0; mi < 8; ++mi) {
    int rg = m0 + wm + mi * 16 + q * 4;
#pragma unroll
    for (int r = 0; r < 4; ++r) {
#pragma unroll
      for (int ni = 0; ni < 4; ++ni) {
        float v = acc[mi][ni][r] + bv[ni];
        if (RELU) v = fmaxf(v, 0.0f);
        C[(size_t)(rg + r) * N + n0 + wn + ni * 16 + rl] = f2bf(v);
      }
    }
  }
}

// ---------------- fused expert stage (bounds-aware, XCD-partitioned) --------

__global__ __launch_bounds__(256, 2) void expert_fused(
    const ushort* __restrict__ Z, const ushort* __restrict__ W1t,
    const float* __restrict__ b1, const float* __restrict__ w2,
    const int* __restrict__ perm, const int* __restrict__ catalog,
    const int* __restrict__ poff, const int* __restrict__ counts,
    float* __restrict__ out) {
  const int id = blockIdx.x;
  const int tile = (id & 7) * 17 + ((id >> 3) >> 4);
  const int ycol = (id >> 3) & 15;
  int e = catalog[tile];
  if (e < 0) return;
  __shared__ __align__(16) ushort lA[128 * 64];
  __shared__ __align__(16) ushort lB[128 * 64];
  __shared__ int perml[128];
  __shared__ float ysum[128];
  const int t = threadIdx.x;
  if (t < 128) {
    int slot = tile * 128 + t;
    int rel = slot - poff[e];
    perml[t] = (rel < counts[e]) ? perm[slot] : -1;
    ysum[t] = 0.0f;
  }
  __syncthreads();

  const int n0 = ycol * 128;
  const ushort* Bt = W1t + (size_t)e * SPEC_H * HID;
  const float* b1e = b1 + (size_t)e * SPEC_H;
  const float* w2e = w2 + (size_t)e * SPEC_H;
  const int w = t >> 6, lane = t & 63;
  const int wm = (w >> 1) * 64, wn = (w & 1) * 64;
  const int q = lane >> 4, rl = lane & 15;

  f32x4 acc[4][4];
#pragma unroll
  for (int mi = 0; mi < 4; ++mi)
#pragma unroll
    for (int ni = 0; ni < 4; ++ni) acc[mi][ni] = 0.0f;

  const int row_s = t >> 3;
  const int pch_s = t & 7;

  for (int k0 = 0; k0 < HID; k0 += 64) {
    __syncthreads();
#pragma unroll
    for (int j = 0; j < 4; ++j) {
      int row = j * 32 + row_s;
      int gch = pch_s ^ (row & 7);
      int zr = perml[row];
      zr = zr < 0 ? 0 : zr;
      gl_lds16(Z + (size_t)zr * HID + k0 + gch * 8, lA + j * 2048 + w * 512);
      gl_lds16(Bt + (size_t)(n0 + row) * HID + k0 + gch * 8, lB + j * 2048 + w * 512);
    }
    __syncthreads();
#pragma unroll
    for (int kk = 0; kk < 2; ++kk) {
      bf16x8 af[4], bfr[4];
#pragma unroll
      for (int i = 0; i < 4; ++i) {
        int pc = (kk * 4 + q) ^ (rl & 7);
        af[i]  = __builtin_bit_cast(bf16x8, *(const int4*)(lA + (wm + i * 16 + rl) * 64 + pc * 8));
        bfr[i] = __builtin_bit_cast(bf16x8, *(const int4*)(lB + (wn + i * 16 + rl) * 64 + pc * 8));
      }
#pragma unroll
      for (int mi = 0; mi < 4; ++mi)
#pragma unroll
        for (int ni = 0; ni < 4; ++ni)
          acc[mi][ni] = __builtin_amdgcn_mfma_f32_16x16x32_bf16(af[mi], bfr[ni], acc[mi][ni], 0, 0, 0);
    }
  }

  float w2v[4], b1v[4];
#pragma unroll
  for (int ni = 0; ni < 4; ++ni) {
    int n = n0 + wn + ni * 16 + rl;
    w2v[ni] = w2e[n];
    b1v[ni] = b1e[n];
  }
#pragma unroll
  for (int mi = 0; mi < 4; ++mi) {
#pragma unroll
    for (int r = 0; r < 4; ++r) {
      float p = 0.0f;
#pragma unroll
      for (int ni = 0; ni < 4; ++ni) {
        float h = acc[mi][ni][r] + b1v[ni];
        h = fmaxf(h, 0.0f);
        p += h * w2v[ni];
      }
      p += __shfl_xor(p, 1);
      p += __shfl_xor(p, 2);
      p += __shfl_xor(p, 4);
      p += __shfl_xor(p, 8);
      if (rl == 0) atomicAdd(&ysum[wm + mi * 16 + q * 4 + r], p);
    }
  }
  __syncthreads();
  if (t < 128) {
    int orow = perml[t];
    if (orow >= 0) atomicAdd(&out[orow], ysum[t]);
  }
}

// ---------------- host ----------------

extern "C" void kernel_launch(void* const* d_in, const int* in_sizes, int n_in,
                              void* d_out, int out_size, void* d_ws, size_t ws_size,
                              hipStream_t stream) {
  const float* x   = (const float*)d_in[0];
  const int*   d   = (const int*)d_in[1];
  const float* eW0 = (const float*)d_in[2];
  const float* eb0 = (const float*)d_in[3];
  const float* eW1 = (const float*)d_in[4];
  const float* eb1 = (const float*)d_in[5];
  const float* eW2 = (const float*)d_in[6];
  const float* eb2 = (const float*)d_in[7];
  const float* sW1 = (const float*)d_in[8];
  const float* sb1 = (const float*)d_in[9];
  const float* sW2 = (const float*)d_in[10];
  const float* sb2 = (const float*)d_in[11];
  float* out = (float*)d_out;

  // fixed: weights bf16 (48 MiB) + Zb (32) + xb (32) + routing (~0.1)
  // per-chunk: z1 + z2 = CH*8192 bytes. Full batch total ~241 MiB.
  const size_t fixed = ((size_t)(4 + 8 + 4 + 32 + 32 + 32) << 20) + (1 << 20);
  int CH = 8192;
  if (ws_size >= fixed + (size_t)16384 * 8192) CH = 16384;   // ~241 MiB

  char* p = (char*)d_ws;
  ushort* W0t  = (ushort*)p; p += (size_t)IN_DIM * H1 * 2;
  ushort* W1t  = (ushort*)p; p += (size_t)H1 * H2 * 2;
  ushort* W2t  = (ushort*)p; p += (size_t)H2 * HID * 2;
  ushort* sW1t = (ushort*)p; p += (size_t)NE * HID * SPEC_H * 2;
  ushort* Zb   = (ushort*)p; p += (size_t)B_SZ * HID * 2;
  ushort* xb   = (ushort*)p; p += (size_t)B_SZ * IN_DIM * 2;
  int* counts  = (int*)p; p += 64;
  int* cursors = (int*)p; p += 64;
  int* poff    = (int*)p; p += 64;
  int* catalog = (int*)p; p += 1024;
  int* perm    = (int*)p; p += (size_t)MAX_TILES * 128 * 4;
  p = (char*)(((uintptr_t)p + 255) & ~(uintptr_t)255);
  ushort* z1 = (ushort*)p; p += (size_t)CH * H1 * 2;
  ushort* z2 = (ushort*)p; p += (size_t)CH * H2 * 2;

  hipMemsetAsync(counts, 0, 64, stream);

  // fused prep: transposes (6144) + x-cast (8192) + count/out-init (64)
  PrepArgs pa;
  pa.td[0] = {eW0, W0t, IN_DIM, H1, H1 / 64, 0};
  pa.td[1] = {eW1, W1t, H1, H2, H2 / 64, 512};
  pa.td[2] = {eW2, W2t, H2, HID, HID / 64, 1536};
  pa.td[3] = {sW1, sW1t, HID, SPEC_H, SPEC_H / 64, 2048};
  pa.x = x; pa.xb = xb;
  pa.d = d; pa.counts = counts; pa.sb2 = sb2; pa.out = out;
  pa.castBase = 6144;
  pa.cntBase = 6144 + 8192;
  prep_all<<<6144 + 8192 + 64, 256, 0, stream>>>(pa);

  build_k<<<1, 64, 0, stream>>>(counts, catalog, poff, cursors);
  scatter_k<<<B_SZ / 256, 256, 0, stream>>>(d, poff, cursors, perm);

  // encoder GEMMs
  for (int c = 0; c < B_SZ; c += CH) {
    gemm_bias<1><<<(CH / 128) * (H1 / 128), 256, 0, stream>>>(
        xb + (size_t)c * IN_DIM, W0t, eb0, z1, CH, H1, IN_DIM, 4);
    gemm_bias_256<1><<<(CH / 256) * (H2 / 128), 256, 0, stream>>>(
        z1, W1t, eb1, z2, CH, H2, H1, 4);
    gemm_bias<0><<<(CH / 128) * (HID / 128), 256, 0, stream>>>(
        z2, W2t, eb2, Zb + (size_t)c * HID, CH, HID, H2, 3);
  }

  // fused expert stage
  expert_fused<<<MAX_TILES * 16, 256, 0, stream>>>(
      Zb, sW1t, sb1, sW2, perm, catalog, poff, counts, out);
}

// Round 8
// 661.763 us; speedup vs baseline: 1.0604x; 1.0018x over previous
//
#include <hip/hip_runtime.h>
#include <hip/hip_bf16.h>
#include <stdint.h>

// Problem constants (match reference)
#define B_SZ   16384
#define IN_DIM 1024
#define H1     2048
#define H2     2048
#define HID    1024
#define SPEC_H 2048
#define NE     8
#define MAX_TILES 136   // 8 XCDs x 17 tiles exactly

typedef __bf16 bf16x8 __attribute__((ext_vector_type(8)));
typedef float  f32x4  __attribute__((ext_vector_type(4)));

__device__ __forceinline__ ushort f2bf(float f) {
  uint32_t u = __float_as_uint(f);
  u += 0x7FFF + ((u >> 16) & 1);
  return (ushort)(u >> 16);
}

__device__ __forceinline__ void gl_lds16(const void* g, void* l) {
  __builtin_amdgcn_global_load_lds(
      (const __attribute__((address_space(1))) void*)g,
      (__attribute__((address_space(3))) void*)l, 16, 0, 0);
}

// ---------------- fused prep: 4 transposes + x-cast + count/out-init --------

struct TransDesc { const float* src; ushort* dst; int K, N, nx, base; };

struct PrepArgs {
  TransDesc td[4];
  const float* x; ushort* xb;
  const int* d; int* counts; const float* sb2; float* out;
  int castBase;   // first cast block
  int cntBase;    // first count block
};

__global__ void prep_all(PrepArgs pa) {
  int g = blockIdx.x;
  int t = threadIdx.x;
  if (g >= pa.cntBase) {
    // count + out-init: 64 blocks x 256
    int i = (g - pa.cntBase) * 256 + t;
    int e = pa.d[i];
    atomicAdd(&pa.counts[e], 1);
    pa.out[i] = pa.sb2[e];     // spec_b2[e][0]
    return;
  }
  if (g >= pa.castBase) {
    // x fp32 -> bf16, 8 elems/thread
    size_t i = (size_t)(g - pa.castBase) * 2048 + (size_t)t * 8;
    float4 v0 = *(const float4*)(pa.x + i);
    float4 v1 = *(const float4*)(pa.x + i + 4);
    uint32_t p0 = f2bf(v0.x) | ((uint32_t)f2bf(v0.y) << 16);
    uint32_t p1 = f2bf(v0.z) | ((uint32_t)f2bf(v0.w) << 16);
    uint32_t p2 = f2bf(v1.x) | ((uint32_t)f2bf(v1.y) << 16);
    uint32_t p3 = f2bf(v1.z) | ((uint32_t)f2bf(v1.w) << 16);
    int4 pk = {(int)p0, (int)p1, (int)p2, (int)p3};
    *(int4*)(pa.xb + i) = pk;
    return;
  }
  // weight transpose-cast
  __shared__ float tile[64][65];  // tile[n][k]
  int wsel = 0;
#pragma unroll
  for (int i = 1; i < 4; ++i)
    if (g >= pa.td[i].base) wsel = i;
  TransDesc dd = pa.td[wsel];
  int local = g - dd.base;
  int per = dd.nx * (dd.K >> 6);
  int z = local / per;
  int r = local - z * per;
  int bx = r % dd.nx, by = r / dd.nx;
  int n0 = bx * 64, k0 = by * 64;
  const float* src = dd.src + (size_t)z * dd.K * dd.N;
  ushort* dst = dd.dst + (size_t)z * dd.K * dd.N;
  int lk = t >> 4;
  int ln4 = (t & 15) * 4;
#pragma unroll
  for (int j = 0; j < 4; ++j) {
    int k = lk + j * 16;
    float4 v = *(const float4*)(src + (size_t)(k0 + k) * dd.N + n0 + ln4);
    tile[ln4 + 0][k] = v.x;
    tile[ln4 + 1][k] = v.y;
    tile[ln4 + 2][k] = v.z;
    tile[ln4 + 3][k] = v.w;
  }
  __syncthreads();
  int kc = (t & 15) * 4;
  int nb = t >> 4;
#pragma unroll
  for (int j = 0; j < 4; ++j) {
    int nn = nb + j * 16;
    ushort4 o;
    o.x = f2bf(tile[nn][kc + 0]);
    o.y = f2bf(tile[nn][kc + 1]);
    o.z = f2bf(tile[nn][kc + 2]);
    o.w = f2bf(tile[nn][kc + 3]);
    *(ushort4*)(dst + (size_t)(n0 + nn) * dd.K + k0 + kc) = o;
  }
}

// ---------------- routing ----------------

__global__ void build_k(const int* __restrict__ counts, int* __restrict__ catalog,
                        int* __restrict__ poff, int* __restrict__ cursors) {
  if (threadIdx.x == 0) {
    int off = 0;
    for (int e = 0; e < NE; ++e) {
      poff[e] = off * 128;
      int nt = (counts[e] + 127) >> 7;
      for (int i = 0; i < nt; ++i) catalog[off + i] = e;
      off += nt;
      cursors[e] = 0;
    }
    for (int i = off; i < MAX_TILES; ++i) catalog[i] = -1;
  }
}

__global__ void scatter_k(const int* __restrict__ d, const int* __restrict__ poff,
                          int* __restrict__ cursors, int* __restrict__ perm) {
  int i = blockIdx.x * 256 + threadIdx.x;
  if (i < B_SZ) {
    int e = d[i];
    int p = atomicAdd(&cursors[e], 1);
    perm[poff[e] + p] = i;
  }
}

// ---------------- 128x128 bf16 GEMM (G1/G3) ----------------

template <int RELU>
__global__ __launch_bounds__(256, 2) void gemm_bias(
    const ushort* __restrict__ A, const ushort* __restrict__ Bt,
    const float* __restrict__ bias, ushort* __restrict__ C,
    int M, int N, int K, int lognx) {
  __shared__ __align__(16) ushort lA[128 * 64];
  __shared__ __align__(16) ushort lB[128 * 64];
  const int t = threadIdx.x;
  const int h = blockIdx.x;
  const int g = h >> 3;
  const int nx = 1 << lognx;
  const int by = (h & 7) + ((g >> lognx) << 3);
  const int bx = g & (nx - 1);
  const int m0 = by * 128, n0 = bx * 128;
  const int w = t >> 6, lane = t & 63;
  const int wm = (w >> 1) * 64, wn = (w & 1) * 64;
  const int q = lane >> 4, rl = lane & 15;

  f32x4 acc[4][4];
#pragma unroll
  for (int mi = 0; mi < 4; ++mi)
#pragma unroll
    for (int ni = 0; ni < 4; ++ni) acc[mi][ni] = 0.0f;

  const int row_s = t >> 3;
  const int pch_s = t & 7;

  for (int k0 = 0; k0 < K; k0 += 64) {
    __syncthreads();
#pragma unroll
    for (int j = 0; j < 4; ++j) {
      int row = j * 32 + row_s;
      int gch = pch_s ^ (row & 7);
      gl_lds16(A + (size_t)(m0 + row) * K + k0 + gch * 8, lA + j * 2048 + w * 512);
      gl_lds16(Bt + (size_t)(n0 + row) * K + k0 + gch * 8, lB + j * 2048 + w * 512);
    }
    __syncthreads();
#pragma unroll
    for (int kk = 0; kk < 2; ++kk) {
      bf16x8 af[4], bfr[4];
#pragma unroll
      for (int i = 0; i < 4; ++i) {
        int pc = (kk * 4 + q) ^ (rl & 7);
        af[i]  = __builtin_bit_cast(bf16x8, *(const int4*)(lA + (wm + i * 16 + rl) * 64 + pc * 8));
        bfr[i] = __builtin_bit_cast(bf16x8, *(const int4*)(lB + (wn + i * 16 + rl) * 64 + pc * 8));
      }
#pragma unroll
      for (int mi = 0; mi < 4; ++mi)
#pragma unroll
        for (int ni = 0; ni < 4; ++ni)
          acc[mi][ni] = __builtin_amdgcn_mfma_f32_16x16x32_bf16(af[mi], bfr[ni], acc[mi][ni], 0, 0, 0);
    }
  }

  float bv[4];
#pragma unroll
  for (int ni = 0; ni < 4; ++ni) bv[ni] = bias[n0 + wn + ni * 16 + rl];
#pragma unroll
  for (int mi = 0; mi < 4; ++mi) {
    int rg = m0 + wm + mi * 16 + q * 4;
#pragma unroll
    for (int r = 0; r < 4; ++r) {
#pragma unroll
      for (int ni = 0; ni < 4; ++ni) {
        float v = acc[mi][ni][r] + bv[ni];
        if (RELU) v = fmaxf(v, 0.0f);
        C[(size_t)(rg + r) * N + n0 + wn + ni * 16 + rl] = f2bf(v);
      }
    }
  }
}

// ---------------- 256x128 bf16 GEMM (G2, launched as two M=8192 halves) -----

template <int RELU>
__global__ __launch_bounds__(256, 2) void gemm_bias_256(
    const ushort* __restrict__ A, const ushort* __restrict__ Bt,
    const float* __restrict__ bias, ushort* __restrict__ C,
    int M, int N, int K, int lognx) {
  __shared__ __align__(16) ushort lA[256 * 64];
  __shared__ __align__(16) ushort lB[128 * 64];
  const int t = threadIdx.x;
  const int h = blockIdx.x;
  const int g = h >> 3;
  const int nx = 1 << lognx;
  const int by = (h & 7) + ((g >> lognx) << 3);
  const int bx = g & (nx - 1);
  const int m0 = by * 256, n0 = bx * 128;
  const int w = t >> 6, lane = t & 63;
  const int wm = (w >> 1) * 128, wn = (w & 1) * 64;
  const int q = lane >> 4, rl = lane & 15;

  f32x4 acc[8][4];
#pragma unroll
  for (int mi = 0; mi < 8; ++mi)
#pragma unroll
    for (int ni = 0; ni < 4; ++ni) acc[mi][ni] = 0.0f;

  const int row_s = t >> 3;
  const int pch_s = t & 7;

  for (int k0 = 0; k0 < K; k0 += 64) {
    __syncthreads();
#pragma unroll
    for (int j = 0; j < 8; ++j) {
      int row = j * 32 + row_s;
      int gch = pch_s ^ (row & 7);
      gl_lds16(A + (size_t)(m0 + row) * K + k0 + gch * 8, lA + j * 2048 + w * 512);
    }
#pragma unroll
    for (int j = 0; j < 4; ++j) {
      int row = j * 32 + row_s;
      int gch = pch_s ^ (row & 7);
      gl_lds16(Bt + (size_t)(n0 + row) * K + k0 + gch * 8, lB + j * 2048 + w * 512);
    }
    __syncthreads();
#pragma unroll
    for (int kk = 0; kk < 2; ++kk) {
      bf16x8 bfr[4];
#pragma unroll
      for (int i = 0; i < 4; ++i) {
        int pc = (kk * 4 + q) ^ (rl & 7);
        bfr[i] = __builtin_bit_cast(bf16x8, *(const int4*)(lB + (wn + i * 16 + rl) * 64 + pc * 8));
      }
#pragma unroll
      for (int mi = 0; mi < 8; ++mi) {
        int pc = (kk * 4 + q) ^ (rl & 7);
        bf16x8 af = __builtin_bit_cast(bf16x8, *(const int4*)(lA + (wm + mi * 16 + rl) * 64 + pc * 8));
#pragma unroll
        for (int ni = 0; ni < 4; ++ni)
          acc[mi][ni] = __builtin_amdgcn_mfma_f32_16x16x32_bf16(af, bfr[ni], acc[mi][ni], 0, 0, 0);
      }
    }
  }

  float bv[4];
#pragma unroll
  for (int ni = 0; ni < 4; ++ni) bv[ni] = bias[n0 + wn + ni * 16 + rl];
#pragma unroll
  for (int mi = 0; mi < 8; ++mi) {
    int rg = m0 + wm + mi * 16 + q * 4;
#pragma unroll
    for (int r = 0; r < 4; ++r) {
#pragma unroll
      for (int ni = 0; ni < 4; ++ni) {
        float v = acc[mi][ni][r] + bv[ni];
        if (RELU) v = fmaxf(v, 0.0f);
        C[(size_t)(rg + r) * N + n0 + wn + ni * 16 + rl] = f2bf(v);
      }
    }
  }
}

// ---------------- fused expert stage (bounds-aware, XCD-partitioned) --------

__global__ __launch_bounds__(256, 2) void expert_fused(
    const ushort* __restrict__ Z, const ushort* __restrict__ W1t,
    const float* __restrict__ b1, const float* __restrict__ w2,
    const int* __restrict__ perm, const int* __restrict__ catalog,
    const int* __restrict__ poff, const int* __restrict__ counts,
    float* __restrict__ out) {
  const int id = blockIdx.x;
  const int tile = (id & 7) * 17 + ((id >> 3) >> 4);
  const int ycol = (id >> 3) & 15;
  int e = catalog[tile];
  if (e < 0) return;
  __shared__ __align__(16) ushort lA[128 * 64];
  __shared__ __align__(16) ushort lB[128 * 64];
  __shared__ int perml[128];
  __shared__ float ysum[128];
  const int t = threadIdx.x;
  if (t < 128) {
    int slot = tile * 128 + t;
    int rel = slot - poff[e];
    perml[t] = (rel < counts[e]) ? perm[slot] : -1;
    ysum[t] = 0.0f;
  }
  __syncthreads();

  const int n0 = ycol * 128;
  const ushort* Bt = W1t + (size_t)e * SPEC_H * HID;
  const float* b1e = b1 + (size_t)e * SPEC_H;
  const float* w2e = w2 + (size_t)e * SPEC_H;
  const int w = t >> 6, lane = t & 63;
  const int wm = (w >> 1) * 64, wn = (w & 1) * 64;
  const int q = lane >> 4, rl = lane & 15;

  f32x4 acc[4][4];
#pragma unroll
  for (int mi = 0; mi < 4; ++mi)
#pragma unroll
    for (int ni = 0; ni < 4; ++ni) acc[mi][ni] = 0.0f;

  const int row_s = t >> 3;
  const int pch_s = t & 7;

  for (int k0 = 0; k0 < HID; k0 += 64) {
    __syncthreads();
#pragma unroll
    for (int j = 0; j < 4; ++j) {
      int row = j * 32 + row_s;
      int gch = pch_s ^ (row & 7);
      int zr = perml[row];
      zr = zr < 0 ? 0 : zr;
      gl_lds16(Z + (size_t)zr * HID + k0 + gch * 8, lA + j * 2048 + w * 512);
      gl_lds16(Bt + (size_t)(n0 + row) * HID + k0 + gch * 8, lB + j * 2048 + w * 512);
    }
    __syncthreads();
#pragma unroll
    for (int kk = 0; kk < 2; ++kk) {
      bf16x8 af[4], bfr[4];
#pragma unroll
      for (int i = 0; i < 4; ++i) {
        int pc = (kk * 4 + q) ^ (rl & 7);
        af[i]  = __builtin_bit_cast(bf16x8, *(const int4*)(lA + (wm + i * 16 + rl) * 64 + pc * 8));
        bfr[i] = __builtin_bit_cast(bf16x8, *(const int4*)(lB + (wn + i * 16 + rl) * 64 + pc * 8));
      }
#pragma unroll
      for (int mi = 0; mi < 4; ++mi)
#pragma unroll
        for (int ni = 0; ni < 4; ++ni)
          acc[mi][ni] = __builtin_amdgcn_mfma_f32_16x16x32_bf16(af[mi], bfr[ni], acc[mi][ni], 0, 0, 0);
    }
  }

  float w2v[4], b1v[4];
#pragma unroll
  for (int ni = 0; ni < 4; ++ni) {
    int n = n0 + wn + ni * 16 + rl;
    w2v[ni] = w2e[n];
    b1v[ni] = b1e[n];
  }
#pragma unroll
  for (int mi = 0; mi < 4; ++mi) {
#pragma unroll
    for (int r = 0; r < 4; ++r) {
      float p = 0.0f;
#pragma unroll
      for (int ni = 0; ni < 4; ++ni) {
        float h = acc[mi][ni][r] + b1v[ni];
        h = fmaxf(h, 0.0f);
        p += h * w2v[ni];
      }
      p += __shfl_xor(p, 1);
      p += __shfl_xor(p, 2);
      p += __shfl_xor(p, 4);
      p += __shfl_xor(p, 8);
      if (rl == 0) atomicAdd(&ysum[wm + mi * 16 + q * 4 + r], p);
    }
  }
  __syncthreads();
  if (t < 128) {
    int orow = perml[t];
    if (orow >= 0) atomicAdd(&out[orow], ysum[t]);
  }
}

// ---------------- host ----------------

extern "C" void kernel_launch(void* const* d_in, const int* in_sizes, int n_in,
                              void* d_out, int out_size, void* d_ws, size_t ws_size,
                              hipStream_t stream) {
  const float* x   = (const float*)d_in[0];
  const int*   d   = (const int*)d_in[1];
  const float* eW0 = (const float*)d_in[2];
  const float* eb0 = (const float*)d_in[3];
  const float* eW1 = (const float*)d_in[4];
  const float* eb1 = (const float*)d_in[5];
  const float* eW2 = (const float*)d_in[6];
  const float* eb2 = (const float*)d_in[7];
  const float* sW1 = (const float*)d_in[8];
  const float* sb1 = (const float*)d_in[9];
  const float* sW2 = (const float*)d_in[10];
  const float* sb2 = (const float*)d_in[11];
  float* out = (float*)d_out;

  const size_t fixed = ((size_t)(4 + 8 + 4 + 32 + 32 + 32) << 20) + (1 << 20);
  int CH = 8192;
  if (ws_size >= fixed + (size_t)16384 * 8192) CH = 16384;   // ~241 MiB

  char* p = (char*)d_ws;
  ushort* W0t  = (ushort*)p; p += (size_t)IN_DIM * H1 * 2;
  ushort* W1t  = (ushort*)p; p += (size_t)H1 * H2 * 2;
  ushort* W2t  = (ushort*)p; p += (size_t)H2 * HID * 2;
  ushort* sW1t = (ushort*)p; p += (size_t)NE * HID * SPEC_H * 2;
  ushort* Zb   = (ushort*)p; p += (size_t)B_SZ * HID * 2;
  ushort* xb   = (ushort*)p; p += (size_t)B_SZ * IN_DIM * 2;
  int* counts  = (int*)p; p += 64;
  int* cursors = (int*)p; p += 64;
  int* poff    = (int*)p; p += 64;
  int* catalog = (int*)p; p += 1024;
  int* perm    = (int*)p; p += (size_t)MAX_TILES * 128 * 4;
  p = (char*)(((uintptr_t)p + 255) & ~(uintptr_t)255);
  ushort* z1 = (ushort*)p; p += (size_t)CH * H1 * 2;
  ushort* z2 = (ushort*)p; p += (size_t)CH * H2 * 2;

  hipMemsetAsync(counts, 0, 64, stream);

  // fused prep: transposes (6144) + x-cast (8192) + count/out-init (64)
  PrepArgs pa;
  pa.td[0] = {eW0, W0t, IN_DIM, H1, H1 / 64, 0};
  pa.td[1] = {eW1, W1t, H1, H2, H2 / 64, 512};
  pa.td[2] = {eW2, W2t, H2, HID, HID / 64, 1536};
  pa.td[3] = {sW1, sW1t, HID, SPEC_H, SPEC_H / 64, 2048};
  pa.x = x; pa.xb = xb;
  pa.d = d; pa.counts = counts; pa.sb2 = sb2; pa.out = out;
  pa.castBase = 6144;
  pa.cntBase = 6144 + 8192;
  prep_all<<<6144 + 8192 + 64, 256, 0, stream>>>(pa);

  build_k<<<1, 64, 0, stream>>>(counts, catalog, poff, cursors);
  scatter_k<<<B_SZ / 256, 256, 0, stream>>>(d, poff, cursors, perm);

  // encoder GEMMs (G2 split into two M=8192 halves: diagnostic — makes the
  // top-5 reveal the true durations of the second-tier dispatches)
  for (int c = 0; c < B_SZ; c += CH) {
    gemm_bias<1><<<(CH / 128) * (H1 / 128), 256, 0, stream>>>(
        xb + (size_t)c * IN_DIM, W0t, eb0, z1, CH, H1, IN_DIM, 4);
    const int HM = CH / 2;  // 8192; (HM/256)%8 == 0 holds
    gemm_bias_256<1><<<(HM / 256) * (H2 / 128), 256, 0, stream>>>(
        z1, W1t, eb1, z2, HM, H2, H1, 4);
    gemm_bias_256<1><<<(HM / 256) * (H2 / 128), 256, 0, stream>>>(
        z1 + (size_t)HM * H1, W1t, eb1, z2 + (size_t)HM * H2, HM, H2, H1, 4);
    gemm_bias<0><<<(CH / 128) * (HID / 128), 256, 0, stream>>>(
        z2, W2t, eb2, Zb + (size_t)c * HID, CH, HID, H2, 3);
  }

  // fused expert stage
  expert_fused<<<MAX_TILES * 16, 256, 0, stream>>>(
      Zb, sW1t, sb1, sW2, perm, catalog, poff, counts, out);
}